// Round 1
// baseline (317.972 us; speedup 1.0000x reference)
//
#include <hip/hip_runtime.h>
#include <stdint.h>

// Problem constants (match reference)
#define T_TOK 1024
#define HDIM  1024
#define IDIM  512
#define NEXP  16
#define ISH   1024      // shared intermediate
#define MAXTILES 96     // >= sum ceil(cnt_e/64) <= 4096/64 + 16 = 80
#define HSLOTS   5120   // >= 4096 + 16*63 padded routed rows

typedef _Float16 f16;
typedef __attribute__((ext_vector_type(8))) _Float16 f16x8;
typedef __attribute__((ext_vector_type(4))) _Float16 f16x4;
typedef __attribute__((ext_vector_type(4))) float    f32x4;

// ---- async global->LDS, 16B per lane. LDS dst is wave-uniform base; HW adds lane*16.
__device__ __forceinline__ void gld16(const void* g, void* l) {
  __builtin_amdgcn_global_load_lds(
      (__attribute__((address_space(1))) void*)(uintptr_t)g,
      (__attribute__((address_space(3))) void*)(uint32_t)(uintptr_t)l,
      16, 0, 0);
}

// ---- LDS tile: 64 rows x 64 halfs, row-major, 16B chunks XOR-swizzled by (row&7)
// so that contiguous global_load_lds staging AND ds_read_b128 frag reads are both
// conflict-balanced (each 4-bank group hit uniformly).
__device__ __forceinline__ f16x8 ldsfrag(const f16* buf, int row, int lch) {
  int phys = lch ^ (row & 7);
  return *(const f16x8*)(buf + row * 64 + phys * 8);
}

// =============== 1. prep: x -> fp16, zero counters ===============
__global__ __launch_bounds__(256) void prep_kernel(const float* __restrict__ x,
                                                   f16* __restrict__ xh,
                                                   int* __restrict__ cnt,
                                                   int* __restrict__ ntiles) {
  int i = blockIdx.x * 256 + threadIdx.x;   // grid 1024 -> exactly T*H/4
  float4 v = ((const float4*)x)[i];
  f16x4 h = { (f16)v.x, (f16)v.y, (f16)v.z, (f16)v.w };
  ((f16x4*)xh)[i] = h;
  if (blockIdx.x == 0) {
    if (threadIdx.x < NEXP) cnt[threadIdx.x] = 0;
    if (threadIdx.x == NEXP) ntiles[0] = 0;
  }
}

// =============== 2. transpose+convert all weights: fp32 [R,C] -> f16 [C,R] ===============
__global__ __launch_bounds__(256) void transpose_all(
    const float* __restrict__ wg, const float* __restrict__ wu, const float* __restrict__ wd,
    const float* __restrict__ sg, const float* __restrict__ su, const float* __restrict__ sd,
    f16* __restrict__ wgT, f16* __restrict__ wuT, f16* __restrict__ wdT,
    f16* __restrict__ sgT, f16* __restrict__ suT, f16* __restrict__ sdT) {
  int z = blockIdx.z;
  const float* src; f16* dst; int R, C;
  if (z < 16)       { src = wg + (size_t)z      * HDIM * IDIM; dst = wgT + (size_t)z      * HDIM * IDIM; R = HDIM; C = IDIM; }
  else if (z < 32)  { src = wu + (size_t)(z-16) * HDIM * IDIM; dst = wuT + (size_t)(z-16) * HDIM * IDIM; R = HDIM; C = IDIM; }
  else if (z < 48)  { src = wd + (size_t)(z-32) * IDIM * HDIM; dst = wdT + (size_t)(z-32) * IDIM * HDIM; R = IDIM; C = HDIM; }
  else if (z == 48) { src = sg; dst = sgT; R = HDIM; C = ISH; }
  else if (z == 49) { src = su; dst = suT; R = HDIM; C = ISH; }
  else              { src = sd; dst = sdT; R = ISH;  C = HDIM; }
  int c0 = blockIdx.x * 64, r0 = blockIdx.y * 64;
  if (c0 >= C || r0 >= R) return;                  // block-uniform guard
  __shared__ float tile[64][65];                   // +1 pad: conflict-free transpose
  int t = threadIdx.x, lc = t & 63, lr0 = t >> 6;
#pragma unroll
  for (int i = 0; i < 16; i++) {
    int lr = lr0 + i * 4;
    tile[lr][lc] = src[(size_t)(r0 + lr) * C + (c0 + lc)];
  }
  __syncthreads();
#pragma unroll
  for (int i = 0; i < 16; i++) {
    int oc = lr0 + i * 4;
    dst[(size_t)(c0 + oc) * R + (r0 + lc)] = (f16)tile[lc][oc];
  }
}

// =============== 3. router: fp32 logits + grouped top-k (exact ref semantics) ===============
__global__ __launch_bounds__(64) void router_kernel(
    const float* __restrict__ x, const float* __restrict__ rw, const float* __restrict__ ebias,
    int* __restrict__ cnt, int* __restrict__ tok, float* __restrict__ tw) {
  int t = blockIdx.x, l = threadIdx.x;
  float acc[16];
#pragma unroll
  for (int e = 0; e < 16; e++) acc[e] = 0.f;
  for (int k = l; k < HDIM; k += 64) {
    float xv = x[(size_t)t * HDIM + k];
    const float4* w4 = (const float4*)(rw + (size_t)k * 16);
#pragma unroll
    for (int q = 0; q < 4; q++) {
      float4 w = w4[q];
      acc[q*4+0] += xv * w.x; acc[q*4+1] += xv * w.y;
      acc[q*4+2] += xv * w.z; acc[q*4+3] += xv * w.w;
    }
  }
#pragma unroll
  for (int off = 32; off >= 1; off >>= 1)
#pragma unroll
    for (int e = 0; e < 16; e++) acc[e] += __shfl_xor(acc[e], off, 64);

  if (l == 0) {
    float s[16], sc[16];
#pragma unroll
    for (int e = 0; e < 16; e++) {
      s[e] = 1.f / (1.f + __expf(-acc[e]));      // sigmoid scores (weights use these)
      sc[e] = s[e] + ebias[e];                    // biased (selection only)
    }
    float gs[4];
#pragma unroll
    for (int g = 0; g < 4; g++) {                 // sum of top-2 per group of 4
      float a = -1e30f, b = -1e30f;
#pragma unroll
      for (int j = 0; j < 4; j++) {
        float v = sc[g*4 + j];
        if (v > a) { b = a; a = v; } else if (v > b) { b = v; }
      }
      gs[g] = a + b;
    }
    int g1 = 0;
    for (int g = 1; g < 4; g++) if (gs[g] > gs[g1]) g1 = g;          // ties -> lowest idx
    int g2 = -1;
    for (int g = 0; g < 4; g++) if (g != g1 && (g2 < 0 || gs[g] > gs[g2])) g2 = g;
    float masked[16];
#pragma unroll
    for (int e = 0; e < 16; e++) {
      int g = e >> 2;
      masked[e] = (g == g1 || g == g2) ? sc[e] : 0.0f;  // exact ref: unselected -> 0.0
    }
    int idx[4]; float wv[4]; float denom = 1e-20f;
#pragma unroll
    for (int j = 0; j < 4; j++) {
      int best = 0; float bv = masked[0];
      for (int e = 1; e < 16; e++) if (masked[e] > bv) { bv = masked[e]; best = e; }
      idx[j] = best; wv[j] = s[best]; denom += s[best];
      masked[best] = -1e30f;
    }
#pragma unroll
    for (int j = 0; j < 4; j++) {
      float wgt = wv[j] / denom * 2.5f;           // fold ROUTED_SCALE here
      int slot = atomicAdd(&cnt[idx[j]], 1);
      tok[idx[j] * T_TOK + slot] = t;
      tw [idx[j] * T_TOK + slot] = wgt;
    }
  }
}

// =============== 4. build padded 64-row tiles per expert ===============
__global__ void build_tiles(const int* __restrict__ cnt, int* __restrict__ tok, float* __restrict__ tw,
                            int* __restrict__ tile_e, int* __restrict__ tile_srow,
                            int* __restrict__ tile_hb, int* __restrict__ ntiles) {
  if (threadIdx.x != 0 || blockIdx.x != 0) return;
  int total = 0, slots = 0;
  for (int e = 0; e < NEXP; e++) {
    int c = cnt[e], nt = (c + 63) >> 6;
    int t0 = (c > 0) ? tok[e * T_TOK] : 0;
    for (int j = 0; j < nt; j++) {
      tile_e[total] = e; tile_srow[total] = j * 64; tile_hb[total] = slots + j * 64; total++;
    }
    for (int s2 = c; s2 < nt * 64; s2++) {        // zero-weight padding rows
      tok[e * T_TOK + s2] = t0; tw[e * T_TOK + s2] = 0.f;
    }
    slots += nt * 64;
  }
  ntiles[0] = total;
}

// =============== GEMM cores: 64x64 tile, BK=64, 4 waves (2x2 of 32x32) ===============
// A [M,K] f16 row-major (K-contig), B^T [N,K] f16 row-major (K-contig).
__device__ __forceinline__ f32x4 mfma16(f16x8 a, f16x8 b, f32x4 c) {
  return __builtin_amdgcn_mfma_f32_16x16x32_f16(a, b, c, 0, 0, 0);
}

template <bool GATHER>
__global__ __launch_bounds__(256) void gu_kernel(
    const f16* __restrict__ A, const f16* __restrict__ Bg0, const f16* __restrict__ Bu0,
    f16* __restrict__ Hdst, int K, int N,
    const int* __restrict__ tile_e, const int* __restrict__ tile_srow,
    const int* __restrict__ tile_hb, const int* __restrict__ ntiles,
    const int* __restrict__ tok) {
  int by = blockIdx.y;
  const f16* Bg = Bg0; const f16* Bu = Bu0;
  int e = 0, srow = 0, mbase = 0;
  if (GATHER) {
    if (by >= ntiles[0]) return;
    e = tile_e[by]; srow = tile_srow[by]; mbase = tile_hb[by];
    size_t bo = (size_t)e * IDIM * HDIM;
    Bg += bo; Bu += bo;
  } else {
    mbase = by * 64;
  }
  int n0 = blockIdx.x * 64;

  __shared__ f16 As[64 * 64], Bgs[64 * 64], Bus[64 * 64];

  int tid = threadIdx.x, lane = tid & 63, wave = tid >> 6;
  int quad = lane >> 4, l15 = lane & 15;
  int r = lane >> 3, p = lane & 7;

  // 24 staging instrs (A:8, Bg:8, Bu:8), 6 per wave; per-lane gptr, uniform LDS base
  const f16* gb[6]; f16* lb[6];
#pragma unroll
  for (int jj = 0; jj < 6; jj++) {
    int j = wave * 6 + jj;
    int buf = j >> 3, i = j & 7;
    int row = i * 8 + r;
    int kcol = (p ^ r) << 3;                       // swizzled k-chunk
    if (buf == 0) {
      int grow = GATHER ? tok[e * T_TOK + srow + row] : (mbase + row);
      gb[jj] = A + (size_t)grow * K + kcol;  lb[jj] = (f16*)As + (i << 9);
    } else if (buf == 1) {
      gb[jj] = Bg + (size_t)(n0 + row) * K + kcol; lb[jj] = (f16*)Bgs + (i << 9);
    } else {
      gb[jj] = Bu + (size_t)(n0 + row) * K + kcol; lb[jj] = (f16*)Bus + (i << 9);
    }
  }

  int wr = wave >> 1, wc = wave & 1;
  int ar0 = 32 * wr + l15, br0 = 32 * wc + l15;
  f32x4 zero = {0.f, 0.f, 0.f, 0.f};
  f32x4 aG[2][2] = {{zero, zero}, {zero, zero}};
  f32x4 aU[2][2] = {{zero, zero}, {zero, zero}};

  for (int kt = 0; kt < K; kt += 64) {
    __syncthreads();
#pragma unroll
    for (int jj = 0; jj < 6; jj++) gld16(gb[jj] + kt, lb[jj]);
    __syncthreads();                               // drains vmcnt: LDS tiles ready
#pragma unroll
    for (int ks = 0; ks < 2; ks++) {
      int lch = (ks << 2) + quad;
      f16x8 a0 = ldsfrag(As,  ar0,      lch);
      f16x8 a1 = ldsfrag(As,  ar0 + 16, lch);
      f16x8 g0 = ldsfrag(Bgs, br0,      lch);
      f16x8 g1 = ldsfrag(Bgs, br0 + 16, lch);
      f16x8 u0 = ldsfrag(Bus, br0,      lch);
      f16x8 u1 = ldsfrag(Bus, br0 + 16, lch);
      aG[0][0] = mfma16(a0, g0, aG[0][0]); aG[0][1] = mfma16(a0, g1, aG[0][1]);
      aG[1][0] = mfma16(a1, g0, aG[1][0]); aG[1][1] = mfma16(a1, g1, aG[1][1]);
      aU[0][0] = mfma16(a0, u0, aU[0][0]); aU[0][1] = mfma16(a0, u1, aU[0][1]);
      aU[1][0] = mfma16(a1, u0, aU[1][0]); aU[1][1] = mfma16(a1, u1, aU[1][1]);
    }
  }
  // epilogue: h = silu(g)*u  (fp32), store f16
#pragma unroll
  for (int mi = 0; mi < 2; mi++)
#pragma unroll
    for (int ni = 0; ni < 2; ni++)
#pragma unroll
      for (int rg = 0; rg < 4; rg++) {
        int m = 32 * wr + 16 * mi + (quad << 2) + rg;   // C/D: row = quad*4+reg
        int n = n0 + 32 * wc + 16 * ni + l15;           //      col = lane&15
        float g = aG[mi][ni][rg], u = aU[mi][ni][rg];
        float val = (g / (1.f + __expf(-g))) * u;
        Hdst[(size_t)(mbase + m) * N + n] = (f16)val;
      }
}

template <bool ROUTED>
__global__ __launch_bounds__(256) void down_kernel(
    const f16* __restrict__ A0, const f16* __restrict__ B0, float* __restrict__ out,
    int K,
    const int* __restrict__ tile_e, const int* __restrict__ tile_srow,
    const int* __restrict__ tile_hb, const int* __restrict__ ntiles,
    const int* __restrict__ tok, const float* __restrict__ tw) {
  int by = blockIdx.y;
  const f16* A = A0; const f16* B = B0;
  int e = 0, srow = 0, abase = 0;
  if (ROUTED) {
    if (by >= ntiles[0]) return;
    e = tile_e[by]; srow = tile_srow[by]; abase = tile_hb[by];
    B += (size_t)e * HDIM * IDIM;
  } else {
    abase = by * 64;
  }
  int n0 = blockIdx.x * 64;

  __shared__ f16 As[64 * 64], Bs[64 * 64];

  int tid = threadIdx.x, lane = tid & 63, wave = tid >> 6;
  int quad = lane >> 4, l15 = lane & 15;
  int r = lane >> 3, p = lane & 7;

  const f16* gb[4]; f16* lb[4];
#pragma unroll
  for (int jj = 0; jj < 4; jj++) {
    int j = wave * 4 + jj;
    int buf = j >> 3, i = j & 7;
    int row = i * 8 + r;
    int kcol = (p ^ r) << 3;
    if (buf == 0) { gb[jj] = A + (size_t)(abase + row) * K + kcol; lb[jj] = (f16*)As + (i << 9); }
    else          { gb[jj] = B + (size_t)(n0 + row) * K + kcol;    lb[jj] = (f16*)Bs + (i << 9); }
  }

  int wr = wave >> 1, wc = wave & 1;
  int ar0 = 32 * wr + l15, br0 = 32 * wc + l15;
  f32x4 zero = {0.f, 0.f, 0.f, 0.f};
  f32x4 ac[2][2] = {{zero, zero}, {zero, zero}};

  for (int kt = 0; kt < K; kt += 64) {
    __syncthreads();
#pragma unroll
    for (int jj = 0; jj < 4; jj++) gld16(gb[jj] + kt, lb[jj]);
    __syncthreads();
#pragma unroll
    for (int ks = 0; ks < 2; ks++) {
      int lch = (ks << 2) + quad;
      f16x8 a0 = ldsfrag(As, ar0,      lch);
      f16x8 a1 = ldsfrag(As, ar0 + 16, lch);
      f16x8 b0 = ldsfrag(Bs, br0,      lch);
      f16x8 b1 = ldsfrag(Bs, br0 + 16, lch);
      ac[0][0] = mfma16(a0, b0, ac[0][0]); ac[0][1] = mfma16(a0, b1, ac[0][1]);
      ac[1][0] = mfma16(a1, b0, ac[1][0]); ac[1][1] = mfma16(a1, b1, ac[1][1]);
    }
  }
#pragma unroll
  for (int mi = 0; mi < 2; mi++)
#pragma unroll
    for (int ni = 0; ni < 2; ni++)
#pragma unroll
      for (int rg = 0; rg < 4; rg++) {
        int m = 32 * wr + 16 * mi + (quad << 2) + rg;
        int n = n0 + 32 * wc + 16 * ni + l15;
        float v = ac[mi][ni][rg];
        if (ROUTED) {
          int sl = e * T_TOK + srow + m;
          atomicAdd(out + (size_t)tok[sl] * HDIM + n, v * tw[sl]);
        } else {
          out[(size_t)(abase + m) * HDIM + n] = v;   // shared expert writes (init) out
        }
      }
}

// =============== launch ===============
extern "C" void kernel_launch(void* const* d_in, const int* in_sizes, int n_in,
                              void* d_out, int out_size, void* d_ws, size_t ws_size,
                              hipStream_t stream) {
  const float* x  = (const float*)d_in[0];
  const float* rw = (const float*)d_in[1];
  const float* eb = (const float*)d_in[2];
  const float* wg = (const float*)d_in[3];
  const float* wu = (const float*)d_in[4];
  const float* wd = (const float*)d_in[5];
  const float* sg = (const float*)d_in[6];
  const float* su = (const float*)d_in[7];
  const float* sd = (const float*)d_in[8];
  float* out = (float*)d_out;
  (void)in_sizes; (void)n_in; (void)out_size; (void)ws_size;  // ws need ~= 63.5 MiB

  char* w = (char*)d_ws;
  size_t off = 0;
  auto alloc = [&](size_t b) { void* p = w + off; off = (off + b + 255) & ~(size_t)255; return p; };

  f16* xh   = (f16*)alloc((size_t)T_TOK * HDIM * 2);
  f16* wgT  = (f16*)alloc((size_t)NEXP * IDIM * HDIM * 2);
  f16* wuT  = (f16*)alloc((size_t)NEXP * IDIM * HDIM * 2);
  f16* wdT  = (f16*)alloc((size_t)NEXP * HDIM * IDIM * 2);
  f16* sgT  = (f16*)alloc((size_t)ISH * HDIM * 2);
  f16* suT  = (f16*)alloc((size_t)ISH * HDIM * 2);
  f16* sdT  = (f16*)alloc((size_t)HDIM * ISH * 2);
  f16* hbuf = (f16*)alloc((size_t)HSLOTS * IDIM * 2);
  f16* hsh  = (f16*)alloc((size_t)T_TOK * ISH * 2);
  int* cnt  = (int*)alloc(NEXP * 4);
  int* tok  = (int*)alloc((size_t)NEXP * T_TOK * 4);
  float* tw = (float*)alloc((size_t)NEXP * T_TOK * 4);
  int* tile_e    = (int*)alloc(MAXTILES * 4);
  int* tile_srow = (int*)alloc(MAXTILES * 4);
  int* tile_hb   = (int*)alloc(MAXTILES * 4);
  int* ntl       = (int*)alloc(16);

  prep_kernel<<<1024, 256, 0, stream>>>(x, xh, cnt, ntl);
  transpose_all<<<dim3(16, 16, 51), 256, 0, stream>>>(wg, wu, wd, sg, su, sd,
                                                      wgT, wuT, wdT, sgT, suT, sdT);
  router_kernel<<<T_TOK, 64, 0, stream>>>(x, rw, eb, cnt, tok, tw);
  build_tiles<<<1, 64, 0, stream>>>(cnt, tok, tw, tile_e, tile_srow, tile_hb, ntl);

  // shared gate+up -> hsh
  gu_kernel<false><<<dim3(ISH / 64, T_TOK / 64), 256, 0, stream>>>(
      xh, sgT, suT, hsh, HDIM, ISH, nullptr, nullptr, nullptr, nullptr, nullptr);
  // routed gate+up -> hbuf
  gu_kernel<true><<<dim3(IDIM / 64, 80), 256, 0, stream>>>(
      xh, wgT, wuT, hbuf, HDIM, IDIM, tile_e, tile_srow, tile_hb, ntl, tok);
  // shared down: writes out (initializes every element)
  down_kernel<false><<<dim3(HDIM / 64, T_TOK / 64), 256, 0, stream>>>(
      hsh, sdT, out, ISH, nullptr, nullptr, nullptr, nullptr, nullptr, nullptr);
  // routed down: atomic add (weight folded, incl. 2.5x)
  down_kernel<true><<<dim3(HDIM / 64, 80), 256, 0, stream>>>(
      hbuf, wdT, out, IDIM, tile_e, tile_srow, tile_hb, ntl, tok, tw);
}

// Round 2
// 280.092 us; speedup vs baseline: 1.1352x; 1.1352x over previous
//
#include <hip/hip_runtime.h>
#include <stdint.h>

// Problem constants (match reference)
#define T_TOK 1024
#define HDIM  1024
#define IDIM  512
#define NEXP  16
#define ISH   1024      // shared intermediate
#define MAXTILES 96     // >= sum ceil(cnt_e/64) <= 4096/64 + 16 = 80
#define HSLOTS   5120   // >= 4096 + 16*63 padded routed rows

typedef _Float16 f16;
typedef __attribute__((ext_vector_type(8))) _Float16 f16x8;
typedef __attribute__((ext_vector_type(4))) _Float16 f16x4;
typedef __attribute__((ext_vector_type(4))) float    f32x4;

// ---- async global->LDS, 16B per lane. LDS dst is wave-uniform base; HW adds lane*16.
__device__ __forceinline__ void gld16(const void* g, void* l) {
  __builtin_amdgcn_global_load_lds(
      (__attribute__((address_space(1))) void*)(uintptr_t)g,
      (__attribute__((address_space(3))) void*)(uint32_t)(uintptr_t)l,
      16, 0, 0);
}

// ---- LDS tile: 64 rows x 64 halfs, 16B chunks XOR-swizzled by (row&7):
// contiguous global_load_lds staging AND ds_read_b128 frag reads both conflict-free.
__device__ __forceinline__ f16x8 ldsfrag(const f16* buf, int row, int lch) {
  int phys = lch ^ (row & 7);
  return *(const f16x8*)(buf + row * 64 + phys * 8);
}

// =============== 1. prep: x -> fp16, zero out ===============
__global__ __launch_bounds__(256) void prep_kernel(const float* __restrict__ x,
                                                   f16* __restrict__ xh,
                                                   float* __restrict__ out) {
  int i = blockIdx.x * 256 + threadIdx.x;   // grid 1024 -> exactly T*H/4 float4
  float4 v = ((const float4*)x)[i];
  f16x4 h = { (f16)v.x, (f16)v.y, (f16)v.z, (f16)v.w };
  ((f16x4*)xh)[i] = h;
  float4 z = {0.f, 0.f, 0.f, 0.f};
  ((float4*)out)[i] = z;                    // out is T*H floats: same count
}

// =============== 2. transpose+convert all weights: fp32 [R,C] -> f16 [C,R] ===============
__global__ __launch_bounds__(256) void transpose_all(
    const float* __restrict__ wg, const float* __restrict__ wu, const float* __restrict__ wd,
    const float* __restrict__ sg, const float* __restrict__ su, const float* __restrict__ sd,
    f16* __restrict__ wgT, f16* __restrict__ wuT, f16* __restrict__ wdT,
    f16* __restrict__ sgT, f16* __restrict__ suT, f16* __restrict__ sdT) {
  int z = blockIdx.z;
  const float* src; f16* dst; int R, C;
  if (z < 16)       { src = wg + (size_t)z      * HDIM * IDIM; dst = wgT + (size_t)z      * HDIM * IDIM; R = HDIM; C = IDIM; }
  else if (z < 32)  { src = wu + (size_t)(z-16) * HDIM * IDIM; dst = wuT + (size_t)(z-16) * HDIM * IDIM; R = HDIM; C = IDIM; }
  else if (z < 48)  { src = wd + (size_t)(z-32) * IDIM * HDIM; dst = wdT + (size_t)(z-32) * IDIM * HDIM; R = IDIM; C = HDIM; }
  else if (z == 48) { src = sg; dst = sgT; R = HDIM; C = ISH; }
  else if (z == 49) { src = su; dst = suT; R = HDIM; C = ISH; }
  else              { src = sd; dst = sdT; R = ISH;  C = HDIM; }
  int c0 = blockIdx.x * 64, r0 = blockIdx.y * 64;
  if (c0 >= C || r0 >= R) return;                  // block-uniform guard
  __shared__ float tile[64][65];                   // +1 pad
  int t = threadIdx.x, lc = t & 63, lr0 = t >> 6;
#pragma unroll
  for (int i = 0; i < 16; i++) {
    int lr = lr0 + i * 4;
    tile[lr][lc] = src[(size_t)(r0 + lr) * C + (c0 + lc)];
  }
  __syncthreads();
  // phase 2: thread -> output col oc = t>>2, rows or0..or0+15; two 16B stores.
  // LDS col reads: bank = (r*65+oc)%32 -> 2-way (free). Stores: lanes 4k..4k+3
  // cover 128 contiguous bytes -> full-line writes.
  int oc = t >> 2, or0 = (t & 3) * 16;
  f16x8 v0, v1;
#pragma unroll
  for (int i = 0; i < 8; i++) {
    v0[i] = (f16)tile[or0 + i][oc];
    v1[i] = (f16)tile[or0 + 8 + i][oc];
  }
  f16* dp = dst + (size_t)(c0 + oc) * R + r0 + or0;
  *(f16x8*)dp = v0;
  *(f16x8*)(dp + 8) = v1;
}

// =============== 3. router GEMV: no atomics, 4 tokens/block ===============
__global__ __launch_bounds__(256) void router_kernel(
    const float* __restrict__ x, const float* __restrict__ rw, const float* __restrict__ ebias,
    int* __restrict__ topk_i, float* __restrict__ topk_w) {
  int wave = threadIdx.x >> 6, l = threadIdx.x & 63;
  int t = blockIdx.x * 4 + wave;
  float acc[16];
#pragma unroll
  for (int e = 0; e < 16; e++) acc[e] = 0.f;
  for (int k = l; k < HDIM; k += 64) {
    float xv = x[(size_t)t * HDIM + k];
    const float4* w4 = (const float4*)(rw + (size_t)k * 16);
#pragma unroll
    for (int q = 0; q < 4; q++) {
      float4 w = w4[q];
      acc[q*4+0] += xv * w.x; acc[q*4+1] += xv * w.y;
      acc[q*4+2] += xv * w.z; acc[q*4+3] += xv * w.w;
    }
  }
#pragma unroll
  for (int off = 32; off >= 1; off >>= 1)
#pragma unroll
    for (int e = 0; e < 16; e++) acc[e] += __shfl_xor(acc[e], off, 64);

  if (l == 0) {
    float s[16], sc[16];
#pragma unroll
    for (int e = 0; e < 16; e++) {
      s[e] = 1.f / (1.f + __expf(-acc[e]));       // sigmoid scores (weights)
      sc[e] = s[e] + ebias[e];                     // biased (selection only)
    }
    float gs[4];
#pragma unroll
    for (int g = 0; g < 4; g++) {                  // sum of top-2 per group of 4
      float a = -1e30f, b = -1e30f;
#pragma unroll
      for (int j = 0; j < 4; j++) {
        float v = sc[g*4 + j];
        if (v > a) { b = a; a = v; } else if (v > b) { b = v; }
      }
      gs[g] = a + b;
    }
    int g1 = 0;
    for (int g = 1; g < 4; g++) if (gs[g] > gs[g1]) g1 = g;   // ties -> lowest idx
    int g2 = -1;
    for (int g = 0; g < 4; g++) if (g != g1 && (g2 < 0 || gs[g] > gs[g2])) g2 = g;
    float masked[16];
#pragma unroll
    for (int e = 0; e < 16; e++) {
      int g = e >> 2;
      masked[e] = (g == g1 || g == g2) ? sc[e] : 0.0f;        // ref: unselected -> 0.0
    }
    int idx[4]; float wv[4]; float denom = 1e-20f;
#pragma unroll
    for (int j = 0; j < 4; j++) {
      int best = 0; float bv = masked[0];
      for (int e = 1; e < 16; e++) if (masked[e] > bv) { bv = masked[e]; best = e; }
      idx[j] = best; wv[j] = s[best]; denom += s[best];
      masked[best] = -1e30f;
    }
#pragma unroll
    for (int j = 0; j < 4; j++) {
      topk_i[t * 4 + j] = idx[j];
      topk_w[t * 4 + j] = wv[j] / denom * 2.5f;   // fold ROUTED_SCALE
    }
  }
}

// =============== 4. scatter: build per-expert lists + tiles (LDS atomics only) ===============
__global__ __launch_bounds__(1024) void scatter_kernel(
    const int* __restrict__ tki, const float* __restrict__ tkw,
    int* __restrict__ tok, float* __restrict__ tw,
    int* __restrict__ tile_e, int* __restrict__ tile_srow,
    int* __restrict__ tile_hb, int* __restrict__ ntl) {
  __shared__ int lcnt[NEXP], lpos[NEXP];
  int t = threadIdx.x;                   // one thread per token
  if (t < NEXP) { lcnt[t] = 0; lpos[t] = 0; }
  __syncthreads();
  int idx[4]; float wv[4];
#pragma unroll
  for (int j = 0; j < 4; j++) { idx[j] = tki[t*4+j]; wv[j] = tkw[t*4+j]; }
#pragma unroll
  for (int j = 0; j < 4; j++) atomicAdd(&lcnt[idx[j]], 1);
  __syncthreads();
  if (t == 0) {                          // tile metadata (tiny serial)
    int total = 0, slots = 0;
    for (int e = 0; e < NEXP; e++) {
      int c = lcnt[e], nt = (c + 63) >> 6;
      for (int j = 0; j < nt; j++) {
        tile_e[total] = e; tile_srow[total] = j * 64; tile_hb[total] = slots + j * 64; total++;
      }
      slots += nt * 64;
    }
    ntl[0] = total;
  }
#pragma unroll
  for (int j = 0; j < 4; j++) {
    int slot = atomicAdd(&lpos[idx[j]], 1);
    tok[idx[j] * T_TOK + slot] = t;
    tw [idx[j] * T_TOK + slot] = wv[j];
  }
  __syncthreads();
  // zero-weight padding rows (token 0 gather, weight 0): <=63 per expert
  int e = t >> 6, s = t & 63;
  int c = lcnt[e];
  int top = ((c + 63) >> 6) << 6;
  int s2 = c + s;
  if (s2 < top) { tok[e * T_TOK + s2] = 0; tw[e * T_TOK + s2] = 0.f; }
}

// =============== GEMM cores: 64x64 tile, BK=64, 4 waves (2x2 of 32x32) ===============
__device__ __forceinline__ f32x4 mfma16(f16x8 a, f16x8 b, f32x4 c) {
  return __builtin_amdgcn_mfma_f32_16x16x32_f16(a, b, c, 0, 0, 0);
}

// gate+up with fused silu; shared (blocks 0..255) + routed gather (blocks 256..)
__global__ __launch_bounds__(256) void gu_all(
    const f16* __restrict__ xh,
    const f16* __restrict__ sgT, const f16* __restrict__ suT, f16* __restrict__ hsh,
    const f16* __restrict__ wgT, const f16* __restrict__ wuT, f16* __restrict__ hbuf,
    const int* __restrict__ tile_e, const int* __restrict__ tile_srow,
    const int* __restrict__ tile_hb, const int* __restrict__ ntl,
    const int* __restrict__ tok) {
  int b = blockIdx.x;
  const f16 *Bg, *Bu; f16* Hdst;
  int e = 0, srow = 0, mbase, n0, N;
  bool gather = (b >= 256);
  if (!gather) {
    Bg = sgT; Bu = suT; Hdst = hsh; N = ISH;
    n0 = (b & 15) * 64; mbase = (b >> 4) * 64;
  } else {
    int rb = b - 256, by = rb >> 3;
    if (by >= ntl[0]) return;
    e = tile_e[by]; srow = tile_srow[by]; mbase = tile_hb[by];
    size_t bo = (size_t)e * IDIM * HDIM;
    Bg = wgT + bo; Bu = wuT + bo; Hdst = hbuf; N = IDIM;
    n0 = (rb & 7) * 64;
  }
  const int K = HDIM;

  __shared__ f16 As[64 * 64], Bgs[64 * 64], Bus[64 * 64];

  int tid = threadIdx.x, lane = tid & 63, wave = tid >> 6;
  int quad = lane >> 4, l15 = lane & 15;
  int r = lane >> 3, p = lane & 7;

  const f16* gb[6]; f16* lb[6];
#pragma unroll
  for (int jj = 0; jj < 6; jj++) {
    int j = wave * 6 + jj;
    int buf = j >> 3, i = j & 7;
    int row = i * 8 + r;
    int kcol = (p ^ r) << 3;                       // swizzled k-chunk
    if (buf == 0) {
      int grow = gather ? tok[e * T_TOK + srow + row] : (mbase + row);
      gb[jj] = xh + (size_t)grow * K + kcol;       lb[jj] = (f16*)As + (i << 9);
    } else if (buf == 1) {
      gb[jj] = Bg + (size_t)(n0 + row) * K + kcol; lb[jj] = (f16*)Bgs + (i << 9);
    } else {
      gb[jj] = Bu + (size_t)(n0 + row) * K + kcol; lb[jj] = (f16*)Bus + (i << 9);
    }
  }

  int wr = wave >> 1, wc = wave & 1;
  int ar0 = 32 * wr + l15, br0 = 32 * wc + l15;
  f32x4 zero = {0.f, 0.f, 0.f, 0.f};
  f32x4 aG[2][2] = {{zero, zero}, {zero, zero}};
  f32x4 aU[2][2] = {{zero, zero}, {zero, zero}};

  for (int kt = 0; kt < K; kt += 64) {
    __syncthreads();
#pragma unroll
    for (int jj = 0; jj < 6; jj++) gld16(gb[jj] + kt, lb[jj]);
    __syncthreads();
#pragma unroll
    for (int ks = 0; ks < 2; ks++) {
      int lch = (ks << 2) + quad;
      f16x8 a0 = ldsfrag(As,  ar0,      lch);
      f16x8 a1 = ldsfrag(As,  ar0 + 16, lch);
      f16x8 g0 = ldsfrag(Bgs, br0,      lch);
      f16x8 g1 = ldsfrag(Bgs, br0 + 16, lch);
      f16x8 u0 = ldsfrag(Bus, br0,      lch);
      f16x8 u1 = ldsfrag(Bus, br0 + 16, lch);
      aG[0][0] = mfma16(a0, g0, aG[0][0]); aG[0][1] = mfma16(a0, g1, aG[0][1]);
      aG[1][0] = mfma16(a1, g0, aG[1][0]); aG[1][1] = mfma16(a1, g1, aG[1][1]);
      aU[0][0] = mfma16(a0, u0, aU[0][0]); aU[0][1] = mfma16(a0, u1, aU[0][1]);
      aU[1][0] = mfma16(a1, u0, aU[1][0]); aU[1][1] = mfma16(a1, u1, aU[1][1]);
    }
  }
#pragma unroll
  for (int mi = 0; mi < 2; mi++)
#pragma unroll
    for (int ni = 0; ni < 2; ni++)
#pragma unroll
      for (int rg = 0; rg < 4; rg++) {
        int m = 32 * wr + 16 * mi + (quad << 2) + rg;   // C/D: row = quad*4+reg
        int n = n0 + 32 * wc + 16 * ni + l15;           //      col = lane&15
        float g = aG[mi][ni][rg], u = aU[mi][ni][rg];
        float val = (g / (1.f + __expf(-g))) * u;
        Hdst[(size_t)(mbase + m) * N + n] = (f16)val;
      }
}

// down proj; shared (blocks 0..255) + routed (blocks 256..); out pre-zeroed -> atomicAdd both
__global__ __launch_bounds__(256) void down_all(
    const f16* __restrict__ hsh, const f16* __restrict__ sdT,
    const f16* __restrict__ hbuf, const f16* __restrict__ wdT,
    float* __restrict__ out,
    const int* __restrict__ tile_e, const int* __restrict__ tile_srow,
    const int* __restrict__ tile_hb, const int* __restrict__ ntl,
    const int* __restrict__ tok, const float* __restrict__ tw) {
  int b = blockIdx.x;
  bool routed = (b >= 256);
  const f16 *A, *B; int K, abase, n0, e = 0, srow = 0;
  if (!routed) {
    A = hsh; B = sdT; K = ISH;
    abase = (b >> 4) * 64; n0 = (b & 15) * 64;
  } else {
    int rb = b - 256, by = rb >> 4;
    if (by >= ntl[0]) return;
    e = tile_e[by]; srow = tile_srow[by]; abase = tile_hb[by];
    A = hbuf; B = wdT + (size_t)e * HDIM * IDIM; K = IDIM;
    n0 = (rb & 15) * 64;
  }

  __shared__ f16 As[64 * 64], Bs[64 * 64];

  int tid = threadIdx.x, lane = tid & 63, wave = tid >> 6;
  int quad = lane >> 4, l15 = lane & 15;
  int r = lane >> 3, p = lane & 7;

  const f16* gb[4]; f16* lb[4];
#pragma unroll
  for (int jj = 0; jj < 4; jj++) {
    int j = wave * 4 + jj;
    int buf = j >> 3, i = j & 7;
    int row = i * 8 + r;
    int kcol = (p ^ r) << 3;
    if (buf == 0) { gb[jj] = A + (size_t)(abase + row) * K + kcol; lb[jj] = (f16*)As + (i << 9); }
    else          { gb[jj] = B + (size_t)(n0 + row) * K + kcol;    lb[jj] = (f16*)Bs + (i << 9); }
  }

  int wr = wave >> 1, wc = wave & 1;
  int ar0 = 32 * wr + l15, br0 = 32 * wc + l15;
  f32x4 zero = {0.f, 0.f, 0.f, 0.f};
  f32x4 ac[2][2] = {{zero, zero}, {zero, zero}};

  for (int kt = 0; kt < K; kt += 64) {
    __syncthreads();
#pragma unroll
    for (int jj = 0; jj < 4; jj++) gld16(gb[jj] + kt, lb[jj]);
    __syncthreads();
#pragma unroll
    for (int ks = 0; ks < 2; ks++) {
      int lch = (ks << 2) + quad;
      f16x8 a0 = ldsfrag(As, ar0,      lch);
      f16x8 a1 = ldsfrag(As, ar0 + 16, lch);
      f16x8 b0 = ldsfrag(Bs, br0,      lch);
      f16x8 b1 = ldsfrag(Bs, br0 + 16, lch);
      ac[0][0] = mfma16(a0, b0, ac[0][0]); ac[0][1] = mfma16(a0, b1, ac[0][1]);
      ac[1][0] = mfma16(a1, b0, ac[1][0]); ac[1][1] = mfma16(a1, b1, ac[1][1]);
    }
  }
#pragma unroll
  for (int mi = 0; mi < 2; mi++)
#pragma unroll
    for (int ni = 0; ni < 2; ni++)
#pragma unroll
      for (int rg = 0; rg < 4; rg++) {
        int m = 32 * wr + 16 * mi + (quad << 2) + rg;
        int n = n0 + 32 * wc + 16 * ni + l15;
        float v = ac[mi][ni][rg];
        if (routed) {
          int sl = e * T_TOK + srow + m;
          atomicAdd(out + (size_t)tok[sl] * HDIM + n, v * tw[sl]);
        } else {
          atomicAdd(out + (size_t)(abase + m) * HDIM + n, v);  // out pre-zeroed
        }
      }
}

// =============== launch ===============
extern "C" void kernel_launch(void* const* d_in, const int* in_sizes, int n_in,
                              void* d_out, int out_size, void* d_ws, size_t ws_size,
                              hipStream_t stream) {
  const float* x  = (const float*)d_in[0];
  const float* rw = (const float*)d_in[1];
  const float* eb = (const float*)d_in[2];
  const float* wg = (const float*)d_in[3];
  const float* wu = (const float*)d_in[4];
  const float* wd = (const float*)d_in[5];
  const float* sg = (const float*)d_in[6];
  const float* su = (const float*)d_in[7];
  const float* sd = (const float*)d_in[8];
  float* out = (float*)d_out;
  (void)in_sizes; (void)n_in; (void)out_size; (void)ws_size;

  char* w = (char*)d_ws;
  size_t off = 0;
  auto alloc = [&](size_t b) { void* p = w + off; off = (off + b + 255) & ~(size_t)255; return p; };

  f16* xh   = (f16*)alloc((size_t)T_TOK * HDIM * 2);
  f16* wgT  = (f16*)alloc((size_t)NEXP * IDIM * HDIM * 2);
  f16* wuT  = (f16*)alloc((size_t)NEXP * IDIM * HDIM * 2);
  f16* wdT  = (f16*)alloc((size_t)NEXP * HDIM * IDIM * 2);
  f16* sgT  = (f16*)alloc((size_t)ISH * HDIM * 2);
  f16* suT  = (f16*)alloc((size_t)ISH * HDIM * 2);
  f16* sdT  = (f16*)alloc((size_t)HDIM * ISH * 2);
  f16* hbuf = (f16*)alloc((size_t)HSLOTS * IDIM * 2);
  f16* hsh  = (f16*)alloc((size_t)T_TOK * ISH * 2);
  int* topk_i = (int*)alloc((size_t)T_TOK * 4 * 4);
  float* topk_w = (float*)alloc((size_t)T_TOK * 4 * 4);
  int* tok  = (int*)alloc((size_t)NEXP * T_TOK * 4);
  float* tw = (float*)alloc((size_t)NEXP * T_TOK * 4);
  int* tile_e    = (int*)alloc(MAXTILES * 4);
  int* tile_srow = (int*)alloc(MAXTILES * 4);
  int* tile_hb   = (int*)alloc(MAXTILES * 4);
  int* ntl       = (int*)alloc(16);

  prep_kernel<<<1024, 256, 0, stream>>>(x, xh, out);
  transpose_all<<<dim3(16, 16, 51), 256, 0, stream>>>(wg, wu, wd, sg, su, sd,
                                                      wgT, wuT, wdT, sgT, suT, sdT);
  router_kernel<<<T_TOK / 4, 256, 0, stream>>>(x, rw, eb, topk_i, topk_w);
  scatter_kernel<<<1, 1024, 0, stream>>>(topk_i, topk_w, tok, tw,
                                         tile_e, tile_srow, tile_hb, ntl);
  // shared gu (256 blocks) + routed gu (640 blocks) in one dispatch
  gu_all<<<256 + (MAXTILES - 16) * 8, 256, 0, stream>>>(
      xh, sgT, suT, hsh, wgT, wuT, hbuf, tile_e, tile_srow, tile_hb, ntl, tok);
  // shared down (256) + routed down (1280) in one dispatch; out pre-zeroed
  down_all<<<256 + (MAXTILES - 16) * 16, 256, 0, stream>>>(
      hsh, sdT, hbuf, wdT, out, tile_e, tile_srow, tile_hb, ntl, tok, tw);
}

// Round 3
// 237.660 us; speedup vs baseline: 1.3379x; 1.1785x over previous
//
#include <hip/hip_runtime.h>
#include <stdint.h>

// Problem constants (match reference)
#define T_TOK 1024
#define HDIM  1024
#define IDIM  512
#define NEXP  16
#define ISH   1024      // shared intermediate
#define MAXTILES 96     // >= sum ceil(cnt_e/64) <= 4096/64 + 16 = 80
#define HSLOTS   5120   // >= 4096 + 16*63 padded routed rows

typedef _Float16 f16;
typedef __attribute__((ext_vector_type(8))) _Float16 f16x8;
typedef __attribute__((ext_vector_type(4))) _Float16 f16x4;
typedef __attribute__((ext_vector_type(4))) float    f32x4;

// ---- async global->LDS, 16B per lane. LDS dst is wave-uniform base; HW adds lane*16.
__device__ __forceinline__ void gld16(const void* g, void* l) {
  __builtin_amdgcn_global_load_lds(
      (__attribute__((address_space(1))) void*)(uintptr_t)g,
      (__attribute__((address_space(3))) void*)(uint32_t)(uintptr_t)l,
      16, 0, 0);
}

// ---- LDS tile: 64 rows x 64 halfs, 16B chunks XOR-swizzled by (row&7):
// contiguous global_load_lds staging AND ds_read_b128 frag reads both conflict-free.
__device__ __forceinline__ f16x8 ldsfrag(const f16* buf, int row, int lch) {
  int phys = lch ^ (row & 7);
  return *(const f16x8*)(buf + row * 64 + phys * 8);
}

// =============== 1. prep: x -> fp16 ===============
__global__ __launch_bounds__(256) void prep_kernel(const float* __restrict__ x,
                                                   f16* __restrict__ xh) {
  int i = blockIdx.x * 256 + threadIdx.x;   // grid 1024 -> exactly T*H/4 float4
  float4 v = ((const float4*)x)[i];
  f16x4 h = { (f16)v.x, (f16)v.y, (f16)v.z, (f16)v.w };
  ((f16x4*)xh)[i] = h;
}

// =============== 2. transpose+convert all weights: fp32 [R,C] -> f16 [C,R] ===============
__global__ __launch_bounds__(256) void transpose_all(
    const float* __restrict__ wg, const float* __restrict__ wu, const float* __restrict__ wd,
    const float* __restrict__ sg, const float* __restrict__ su, const float* __restrict__ sd,
    f16* __restrict__ wgT, f16* __restrict__ wuT, f16* __restrict__ wdT,
    f16* __restrict__ sgT, f16* __restrict__ suT, f16* __restrict__ sdT) {
  int z = blockIdx.z;
  const float* src; f16* dst; int R, C;
  if (z < 16)       { src = wg + (size_t)z      * HDIM * IDIM; dst = wgT + (size_t)z      * HDIM * IDIM; R = HDIM; C = IDIM; }
  else if (z < 32)  { src = wu + (size_t)(z-16) * HDIM * IDIM; dst = wuT + (size_t)(z-16) * HDIM * IDIM; R = HDIM; C = IDIM; }
  else if (z < 48)  { src = wd + (size_t)(z-32) * IDIM * HDIM; dst = wdT + (size_t)(z-32) * IDIM * HDIM; R = IDIM; C = HDIM; }
  else if (z == 48) { src = sg; dst = sgT; R = HDIM; C = ISH; }
  else if (z == 49) { src = su; dst = suT; R = HDIM; C = ISH; }
  else              { src = sd; dst = sdT; R = ISH;  C = HDIM; }
  int c0 = blockIdx.x * 64, r0 = blockIdx.y * 64;
  if (c0 >= C || r0 >= R) return;                  // block-uniform guard
  __shared__ float tile[64][65];                   // +1 pad
  int t = threadIdx.x, lc = t & 63, lr0 = t >> 6;
#pragma unroll
  for (int i = 0; i < 16; i++) {
    int lr = lr0 + i * 4;
    tile[lr][lc] = src[(size_t)(r0 + lr) * C + (c0 + lc)];
  }
  __syncthreads();
  // phase 2: thread -> output col oc = t>>2, rows or0..or0+15; two 16B stores.
  int oc = t >> 2, or0 = (t & 3) * 16;
  f16x8 v0, v1;
#pragma unroll
  for (int i = 0; i < 8; i++) {
    v0[i] = (f16)tile[or0 + i][oc];
    v1[i] = (f16)tile[or0 + 8 + i][oc];
  }
  f16* dp = dst + (size_t)(c0 + oc) * R + r0 + or0;
  *(f16x8*)dp = v0;
  *(f16x8*)(dp + 8) = v1;
}

// =============== 3. router GEMV: no atomics, 4 tokens/block ===============
__global__ __launch_bounds__(256) void router_kernel(
    const float* __restrict__ x, const float* __restrict__ rw, const float* __restrict__ ebias,
    int* __restrict__ topk_i, float* __restrict__ topk_w) {
  int wave = threadIdx.x >> 6, l = threadIdx.x & 63;
  int t = blockIdx.x * 4 + wave;
  float acc[16];
#pragma unroll
  for (int e = 0; e < 16; e++) acc[e] = 0.f;
  for (int k = l; k < HDIM; k += 64) {
    float xv = x[(size_t)t * HDIM + k];
    const float4* w4 = (const float4*)(rw + (size_t)k * 16);
#pragma unroll
    for (int q = 0; q < 4; q++) {
      float4 w = w4[q];
      acc[q*4+0] += xv * w.x; acc[q*4+1] += xv * w.y;
      acc[q*4+2] += xv * w.z; acc[q*4+3] += xv * w.w;
    }
  }
#pragma unroll
  for (int off = 32; off >= 1; off >>= 1)
#pragma unroll
    for (int e = 0; e < 16; e++) acc[e] += __shfl_xor(acc[e], off, 64);

  if (l == 0) {
    float s[16], sc[16];
#pragma unroll
    for (int e = 0; e < 16; e++) {
      s[e] = 1.f / (1.f + __expf(-acc[e]));       // sigmoid scores (weights)
      sc[e] = s[e] + ebias[e];                     // biased (selection only)
    }
    float gs[4];
#pragma unroll
    for (int g = 0; g < 4; g++) {                  // sum of top-2 per group of 4
      float a = -1e30f, b = -1e30f;
#pragma unroll
      for (int j = 0; j < 4; j++) {
        float v = sc[g*4 + j];
        if (v > a) { b = a; a = v; } else if (v > b) { b = v; }
      }
      gs[g] = a + b;
    }
    int g1 = 0;
    for (int g = 1; g < 4; g++) if (gs[g] > gs[g1]) g1 = g;   // ties -> lowest idx
    int g2 = -1;
    for (int g = 0; g < 4; g++) if (g != g1 && (g2 < 0 || gs[g] > gs[g2])) g2 = g;
    float masked[16];
#pragma unroll
    for (int e = 0; e < 16; e++) {
      int g = e >> 2;
      masked[e] = (g == g1 || g == g2) ? sc[e] : 0.0f;        // ref: unselected -> 0.0
    }
    int idx[4]; float wv[4]; float denom = 1e-20f;
#pragma unroll
    for (int j = 0; j < 4; j++) {
      int best = 0; float bv = masked[0];
      for (int e = 1; e < 16; e++) if (masked[e] > bv) { bv = masked[e]; best = e; }
      idx[j] = best; wv[j] = s[best]; denom += s[best];
      masked[best] = -1e30f;
    }
#pragma unroll
    for (int j = 0; j < 4; j++) {
      topk_i[t * 4 + j] = idx[j];
      topk_w[t * 4 + j] = wv[j] / denom * 2.5f;   // fold ROUTED_SCALE
    }
  }
}

// =============== 4. scatter: per-expert lists + tiles + slot map (LDS atomics) ===============
__global__ __launch_bounds__(1024) void scatter_kernel(
    const int* __restrict__ tki,
    int* __restrict__ tok, int* __restrict__ slotmap,
    int* __restrict__ tile_e, int* __restrict__ tile_srow,
    int* __restrict__ tile_hb, int* __restrict__ ntl) {
  __shared__ int lcnt[NEXP], lpos[NEXP], lbase[NEXP];
  int t = threadIdx.x;                   // one thread per token
  if (t < NEXP) { lcnt[t] = 0; lpos[t] = 0; }
  __syncthreads();
  int idx[4];
#pragma unroll
  for (int j = 0; j < 4; j++) idx[j] = tki[t*4+j];
#pragma unroll
  for (int j = 0; j < 4; j++) atomicAdd(&lcnt[idx[j]], 1);
  __syncthreads();
  if (t == 0) {                          // tile metadata (tiny serial)
    int total = 0, slots = 0;
    for (int e = 0; e < NEXP; e++) {
      int c = lcnt[e], nt = (c + 63) >> 6;
      lbase[e] = slots;
      for (int j = 0; j < nt; j++) {
        tile_e[total] = e; tile_srow[total] = j * 64; tile_hb[total] = slots + j * 64; total++;
      }
      slots += nt * 64;
    }
    ntl[0] = total;
  }
  __syncthreads();
#pragma unroll
  for (int j = 0; j < 4; j++) {
    int slot = atomicAdd(&lpos[idx[j]], 1);
    tok[idx[j] * T_TOK + slot] = t;
    slotmap[t * 4 + j] = lbase[idx[j]] + slot;   // hbuf/odown row of this assignment
  }
  __syncthreads();
  // padding rows gather token 0 (results never read by combine)
  int e = t >> 6, s = t & 63;
  int c = lcnt[e];
  int top = ((c + 63) >> 6) << 6;
  if (c + s < top) tok[e * T_TOK + c + s] = 0;
}

// =============== GEMM cores: 64x64 tile, BK=64, 4 waves (2x2 of 32x32) ===============
__device__ __forceinline__ f32x4 mfma16(f16x8 a, f16x8 b, f32x4 c) {
  return __builtin_amdgcn_mfma_f32_16x16x32_f16(a, b, c, 0, 0, 0);
}

// gate+up with fused silu; shared (blocks 0..255) + routed gather (blocks 256..)
__global__ __launch_bounds__(256) void gu_all(
    const f16* __restrict__ xh,
    const f16* __restrict__ sgT, const f16* __restrict__ suT, f16* __restrict__ hsh,
    const f16* __restrict__ wgT, const f16* __restrict__ wuT, f16* __restrict__ hbuf,
    const int* __restrict__ tile_e, const int* __restrict__ tile_srow,
    const int* __restrict__ tile_hb, const int* __restrict__ ntl,
    const int* __restrict__ tok) {
  int b = blockIdx.x;
  const f16 *Bg, *Bu; f16* Hdst;
  int e = 0, srow = 0, mbase, n0, N;
  bool gather = (b >= 256);
  if (!gather) {
    Bg = sgT; Bu = suT; Hdst = hsh; N = ISH;
    n0 = (b & 15) * 64; mbase = (b >> 4) * 64;
  } else {
    int rb = b - 256, by = rb >> 3;
    if (by >= ntl[0]) return;
    e = tile_e[by]; srow = tile_srow[by]; mbase = tile_hb[by];
    size_t bo = (size_t)e * IDIM * HDIM;
    Bg = wgT + bo; Bu = wuT + bo; Hdst = hbuf; N = IDIM;
    n0 = (rb & 7) * 64;
  }
  const int K = HDIM;

  __shared__ f16 As[64 * 64], Bgs[64 * 64], Bus[64 * 64];

  int tid = threadIdx.x, lane = tid & 63, wave = tid >> 6;
  int quad = lane >> 4, l15 = lane & 15;
  int r = lane >> 3, p = lane & 7;

  const f16* gb[6]; f16* lb[6];
#pragma unroll
  for (int jj = 0; jj < 6; jj++) {
    int j = wave * 6 + jj;
    int buf = j >> 3, i = j & 7;
    int row = i * 8 + r;
    int kcol = (p ^ r) << 3;                       // swizzled k-chunk
    if (buf == 0) {
      int grow = gather ? tok[e * T_TOK + srow + row] : (mbase + row);
      gb[jj] = xh + (size_t)grow * K + kcol;       lb[jj] = (f16*)As + (i << 9);
    } else if (buf == 1) {
      gb[jj] = Bg + (size_t)(n0 + row) * K + kcol; lb[jj] = (f16*)Bgs + (i << 9);
    } else {
      gb[jj] = Bu + (size_t)(n0 + row) * K + kcol; lb[jj] = (f16*)Bus + (i << 9);
    }
  }

  int wr = wave >> 1, wc = wave & 1;
  int ar0 = 32 * wr + l15, br0 = 32 * wc + l15;
  f32x4 zero = {0.f, 0.f, 0.f, 0.f};
  f32x4 aG[2][2] = {{zero, zero}, {zero, zero}};
  f32x4 aU[2][2] = {{zero, zero}, {zero, zero}};

  for (int kt = 0; kt < K; kt += 64) {
    __syncthreads();
#pragma unroll
    for (int jj = 0; jj < 6; jj++) gld16(gb[jj] + kt, lb[jj]);
    __syncthreads();
#pragma unroll
    for (int ks = 0; ks < 2; ks++) {
      int lch = (ks << 2) + quad;
      f16x8 a0 = ldsfrag(As,  ar0,      lch);
      f16x8 a1 = ldsfrag(As,  ar0 + 16, lch);
      f16x8 g0 = ldsfrag(Bgs, br0,      lch);
      f16x8 g1 = ldsfrag(Bgs, br0 + 16, lch);
      f16x8 u0 = ldsfrag(Bus, br0,      lch);
      f16x8 u1 = ldsfrag(Bus, br0 + 16, lch);
      aG[0][0] = mfma16(a0, g0, aG[0][0]); aG[0][1] = mfma16(a0, g1, aG[0][1]);
      aG[1][0] = mfma16(a1, g0, aG[1][0]); aG[1][1] = mfma16(a1, g1, aG[1][1]);
      aU[0][0] = mfma16(a0, u0, aU[0][0]); aU[0][1] = mfma16(a0, u1, aU[0][1]);
      aU[1][0] = mfma16(a1, u0, aU[1][0]); aU[1][1] = mfma16(a1, u1, aU[1][1]);
    }
  }
#pragma unroll
  for (int mi = 0; mi < 2; mi++)
#pragma unroll
    for (int ni = 0; ni < 2; ni++)
#pragma unroll
      for (int rg = 0; rg < 4; rg++) {
        int m = 32 * wr + 16 * mi + (quad << 2) + rg;   // C/D: row = quad*4+reg
        int n = n0 + 32 * wc + 16 * ni + l15;           //      col = lane&15
        float g = aG[mi][ni][rg], u = aU[mi][ni][rg];
        float val = (g / (1.f + __expf(-g))) * u;
        Hdst[(size_t)(mbase + m) * N + n] = (f16)val;
      }
}

// down proj; shared (blocks 0..255) -> out plain stores; routed -> odown plain stores
__global__ __launch_bounds__(256) void down_all(
    const f16* __restrict__ hsh, const f16* __restrict__ sdT,
    const f16* __restrict__ hbuf, const f16* __restrict__ wdT,
    float* __restrict__ out, float* __restrict__ odown,
    const int* __restrict__ tile_e, const int* __restrict__ tile_srow,
    const int* __restrict__ tile_hb, const int* __restrict__ ntl) {
  int b = blockIdx.x;
  bool routed = (b >= 256);
  const f16 *A, *B; int K, abase, n0, e = 0;
  if (!routed) {
    A = hsh; B = sdT; K = ISH;
    abase = (b >> 4) * 64; n0 = (b & 15) * 64;
  } else {
    int rb = b - 256, by = rb >> 4;
    if (by >= ntl[0]) return;
    e = tile_e[by]; abase = tile_hb[by];
    A = hbuf; B = wdT + (size_t)e * HDIM * IDIM; K = IDIM;
    n0 = (rb & 15) * 64;
  }

  __shared__ f16 As[64 * 64], Bs[64 * 64];

  int tid = threadIdx.x, lane = tid & 63, wave = tid >> 6;
  int quad = lane >> 4, l15 = lane & 15;
  int r = lane >> 3, p = lane & 7;

  const f16* gb[4]; f16* lb[4];
#pragma unroll
  for (int jj = 0; jj < 4; jj++) {
    int j = wave * 4 + jj;
    int buf = j >> 3, i = j & 7;
    int row = i * 8 + r;
    int kcol = (p ^ r) << 3;
    if (buf == 0) { gb[jj] = A + (size_t)(abase + row) * K + kcol; lb[jj] = (f16*)As + (i << 9); }
    else          { gb[jj] = B + (size_t)(n0 + row) * K + kcol;    lb[jj] = (f16*)Bs + (i << 9); }
  }

  int wr = wave >> 1, wc = wave & 1;
  int ar0 = 32 * wr + l15, br0 = 32 * wc + l15;
  f32x4 zero = {0.f, 0.f, 0.f, 0.f};
  f32x4 ac[2][2] = {{zero, zero}, {zero, zero}};

  for (int kt = 0; kt < K; kt += 64) {
    __syncthreads();
#pragma unroll
    for (int jj = 0; jj < 4; jj++) gld16(gb[jj] + kt, lb[jj]);
    __syncthreads();
#pragma unroll
    for (int ks = 0; ks < 2; ks++) {
      int lch = (ks << 2) + quad;
      f16x8 a0 = ldsfrag(As, ar0,      lch);
      f16x8 a1 = ldsfrag(As, ar0 + 16, lch);
      f16x8 b0 = ldsfrag(Bs, br0,      lch);
      f16x8 b1 = ldsfrag(Bs, br0 + 16, lch);
      ac[0][0] = mfma16(a0, b0, ac[0][0]); ac[0][1] = mfma16(a0, b1, ac[0][1]);
      ac[1][0] = mfma16(a1, b0, ac[1][0]); ac[1][1] = mfma16(a1, b1, ac[1][1]);
    }
  }
  float* dst = routed ? odown : out;
#pragma unroll
  for (int mi = 0; mi < 2; mi++)
#pragma unroll
    for (int ni = 0; ni < 2; ni++)
#pragma unroll
      for (int rg = 0; rg < 4; rg++) {
        int m = 32 * wr + 16 * mi + (quad << 2) + rg;
        int n = n0 + 32 * wc + 16 * ni + l15;
        dst[(size_t)(abase + m) * HDIM + n] = ac[mi][ni][rg];
      }
}

// =============== combine: out[t] += sum_j w_j * odown[slot(t,j)] ===============
__global__ __launch_bounds__(256) void combine_kernel(
    const float* __restrict__ odown, const int* __restrict__ slotmap,
    const float* __restrict__ tkw, float* __restrict__ out) {
  int t = blockIdx.x;
  __shared__ int ss[4]; __shared__ float sw[4];
  if (threadIdx.x < 4) {
    ss[threadIdx.x] = slotmap[t * 4 + threadIdx.x];
    sw[threadIdx.x] = tkw[t * 4 + threadIdx.x];
  }
  __syncthreads();
  int h = threadIdx.x * 4;
  float4 acc = *(const float4*)(out + (size_t)t * HDIM + h);
#pragma unroll
  for (int j = 0; j < 4; j++) {
    float4 v = *(const float4*)(odown + (size_t)ss[j] * HDIM + h);
    float wj = sw[j];
    acc.x += wj * v.x; acc.y += wj * v.y; acc.z += wj * v.z; acc.w += wj * v.w;
  }
  *(float4*)(out + (size_t)t * HDIM + h) = acc;
}

// =============== launch ===============
extern "C" void kernel_launch(void* const* d_in, const int* in_sizes, int n_in,
                              void* d_out, int out_size, void* d_ws, size_t ws_size,
                              hipStream_t stream) {
  const float* x  = (const float*)d_in[0];
  const float* rw = (const float*)d_in[1];
  const float* eb = (const float*)d_in[2];
  const float* wg = (const float*)d_in[3];
  const float* wu = (const float*)d_in[4];
  const float* wd = (const float*)d_in[5];
  const float* sg = (const float*)d_in[6];
  const float* su = (const float*)d_in[7];
  const float* sd = (const float*)d_in[8];
  float* out = (float*)d_out;
  (void)in_sizes; (void)n_in; (void)out_size; (void)ws_size;

  char* w = (char*)d_ws;
  size_t off = 0;
  auto alloc = [&](size_t b) { void* p = w + off; off = (off + b + 255) & ~(size_t)255; return p; };

  f16* xh   = (f16*)alloc((size_t)T_TOK * HDIM * 2);
  f16* wgT  = (f16*)alloc((size_t)NEXP * IDIM * HDIM * 2);
  f16* wuT  = (f16*)alloc((size_t)NEXP * IDIM * HDIM * 2);
  f16* wdT  = (f16*)alloc((size_t)NEXP * HDIM * IDIM * 2);
  f16* sgT  = (f16*)alloc((size_t)ISH * HDIM * 2);
  f16* suT  = (f16*)alloc((size_t)ISH * HDIM * 2);
  f16* sdT  = (f16*)alloc((size_t)HDIM * ISH * 2);
  f16* hbuf = (f16*)alloc((size_t)HSLOTS * IDIM * 2);
  f16* hsh  = (f16*)alloc((size_t)T_TOK * ISH * 2);
  int* topk_i = (int*)alloc((size_t)T_TOK * 4 * 4);
  float* topk_w = (float*)alloc((size_t)T_TOK * 4 * 4);
  int* tok  = (int*)alloc((size_t)NEXP * T_TOK * 4);
  int* slotmap = (int*)alloc((size_t)T_TOK * 4 * 4);
  int* tile_e    = (int*)alloc(MAXTILES * 4);
  int* tile_srow = (int*)alloc(MAXTILES * 4);
  int* tile_hb   = (int*)alloc(MAXTILES * 4);
  int* ntl       = (int*)alloc(16);
  // odown (fp32, HSLOTS x HDIM = 20 MB) aliases wgT+wuT (32 MB): wgT/wuT are dead
  // after gu_all completes, and down_all (writer) is stream-ordered after it.
  float* odown = (float*)wgT;

  prep_kernel<<<1024, 256, 0, stream>>>(x, xh);
  transpose_all<<<dim3(16, 16, 51), 256, 0, stream>>>(wg, wu, wd, sg, su, sd,
                                                      wgT, wuT, wdT, sgT, suT, sdT);
  router_kernel<<<T_TOK / 4, 256, 0, stream>>>(x, rw, eb, topk_i, topk_w);
  scatter_kernel<<<1, 1024, 0, stream>>>(topk_i, tok, slotmap,
                                         tile_e, tile_srow, tile_hb, ntl);
  // shared gu (256 blocks) + routed gu (640 blocks) in one dispatch
  gu_all<<<256 + (MAXTILES - 16) * 8, 256, 0, stream>>>(
      xh, sgT, suT, hsh, wgT, wuT, hbuf, tile_e, tile_srow, tile_hb, ntl, tok);
  // shared down (256) -> out stores; routed down (1280) -> odown stores
  down_all<<<256 + (MAXTILES - 16) * 16, 256, 0, stream>>>(
      hsh, sdT, hbuf, wdT, out, odown, tile_e, tile_srow, tile_hb, ntl);
  // out[t] += sum_j w_j * odown[slot]
  combine_kernel<<<T_TOK, 256, 0, stream>>>(odown, slotmap, topk_w, out);
}

// Round 4
// 229.097 us; speedup vs baseline: 1.3879x; 1.0374x over previous
//
#include <hip/hip_runtime.h>
#include <stdint.h>

// Problem constants (match reference)
#define T_TOK 1024
#define HDIM  1024
#define IDIM  512
#define NEXP  16
#define ISH   1024      // shared intermediate
#define MAXTILES 96     // >= sum ceil(cnt_e/64) <= 4096/64 + 16 = 80
#define HSLOTS   5120   // >= 4096 + 16*63 padded routed rows

typedef _Float16 f16;
typedef __attribute__((ext_vector_type(8))) _Float16 f16x8;
typedef __attribute__((ext_vector_type(4))) _Float16 f16x4;
typedef __attribute__((ext_vector_type(4))) float    f32x4;

// ---- async global->LDS, 16B per lane. LDS dst is wave-uniform base; HW adds lane*16.
__device__ __forceinline__ void gld16(const void* g, void* l) {
  __builtin_amdgcn_global_load_lds(
      (__attribute__((address_space(1))) void*)(uintptr_t)g,
      (__attribute__((address_space(3))) void*)(uint32_t)(uintptr_t)l,
      16, 0, 0);
}

// ---- LDS tile: 64 rows x 64 halfs, 16B chunks XOR-swizzled by (row&7):
// contiguous global_load_lds staging AND ds_read_b128 frag reads both conflict-free.
__device__ __forceinline__ f16x8 ldsfrag(const f16* buf, int row, int lch) {
  int phys = lch ^ (row & 7);
  return *(const f16x8*)(buf + row * 64 + phys * 8);
}

// =============== transpose+convert all weights: fp32 [R,C] -> f16 [C,R] ===============
// Phase 1: float4 loads (16B/lane; 1KB per wave-instr). Banks (65r+c)%32=(r+c)%32:
// r in 0..3, c4 in {0,4..60} per wave -> 2-way, free. Phase 2: 2-way free, f16x8 stores.
__global__ __launch_bounds__(256) void transpose_all(
    const float* __restrict__ wg, const float* __restrict__ wu, const float* __restrict__ wd,
    const float* __restrict__ sg, const float* __restrict__ su, const float* __restrict__ sd,
    f16* __restrict__ wgT, f16* __restrict__ wuT, f16* __restrict__ wdT,
    f16* __restrict__ sgT, f16* __restrict__ suT, f16* __restrict__ sdT) {
  int z = blockIdx.z;
  const float* src; f16* dst; int R, C;
  if (z < 16)       { src = wg + (size_t)z      * HDIM * IDIM; dst = wgT + (size_t)z      * HDIM * IDIM; R = HDIM; C = IDIM; }
  else if (z < 32)  { src = wu + (size_t)(z-16) * HDIM * IDIM; dst = wuT + (size_t)(z-16) * HDIM * IDIM; R = HDIM; C = IDIM; }
  else if (z < 48)  { src = wd + (size_t)(z-32) * IDIM * HDIM; dst = wdT + (size_t)(z-32) * IDIM * HDIM; R = IDIM; C = HDIM; }
  else if (z == 48) { src = sg; dst = sgT; R = HDIM; C = ISH; }
  else if (z == 49) { src = su; dst = suT; R = HDIM; C = ISH; }
  else              { src = sd; dst = sdT; R = ISH;  C = HDIM; }
  int c0 = blockIdx.x * 64, r0 = blockIdx.y * 64;
  if (c0 >= C || r0 >= R) return;                  // block-uniform guard
  __shared__ float tile[64][65];                   // +1 pad
  int t = threadIdx.x;
  int lr = t >> 4, c4 = (t & 15) * 4;
#pragma unroll
  for (int pass = 0; pass < 4; pass++) {
    int r = pass * 16 + lr;
    float4 v = *(const float4*)(src + (size_t)(r0 + r) * C + (c0 + c4));
    tile[r][c4 + 0] = v.x; tile[r][c4 + 1] = v.y;
    tile[r][c4 + 2] = v.z; tile[r][c4 + 3] = v.w;
  }
  __syncthreads();
  // phase 2: thread -> output col oc = t>>2, rows or0..or0+15; two 16B stores.
  int oc = t >> 2, or0 = (t & 3) * 16;
  f16x8 v0, v1;
#pragma unroll
  for (int i = 0; i < 8; i++) {
    v0[i] = (f16)tile[or0 + i][oc];
    v1[i] = (f16)tile[or0 + 8 + i][oc];
  }
  f16* dp = dst + (size_t)(c0 + oc) * R + r0 + or0;
  *(f16x8*)dp = v0;
  *(f16x8*)(dp + 8) = v1;
}

// =============== router GEMV (also emits xh = f16(x)): 4 tokens/block ===============
__global__ __launch_bounds__(256) void router_kernel(
    const float* __restrict__ x, const float* __restrict__ rw, const float* __restrict__ ebias,
    f16* __restrict__ xh, int* __restrict__ topk_i, float* __restrict__ topk_w) {
  int wave = threadIdx.x >> 6, l = threadIdx.x & 63;
  int t = blockIdx.x * 4 + wave;
  float acc[16];
#pragma unroll
  for (int e = 0; e < 16; e++) acc[e] = 0.f;
#pragma unroll
  for (int i = 0; i < 4; i++) {
    int k = i * 256 + l * 4;
    float4 xv = *(const float4*)(x + (size_t)t * HDIM + k);
    f16x4 h = { (f16)xv.x, (f16)xv.y, (f16)xv.z, (f16)xv.w };
    *(f16x4*)(xh + (size_t)t * HDIM + k) = h;
    const float* xp = &xv.x;
#pragma unroll
    for (int j = 0; j < 4; j++) {
      float xj = xp[j];
      const float4* w4 = (const float4*)(rw + (size_t)(k + j) * 16);
#pragma unroll
      for (int q = 0; q < 4; q++) {
        float4 w = w4[q];
        acc[q*4+0] += xj * w.x; acc[q*4+1] += xj * w.y;
        acc[q*4+2] += xj * w.z; acc[q*4+3] += xj * w.w;
      }
    }
  }
#pragma unroll
  for (int off = 32; off >= 1; off >>= 1)
#pragma unroll
    for (int e = 0; e < 16; e++) acc[e] += __shfl_xor(acc[e], off, 64);

  if (l == 0) {
    float s[16], sc[16];
#pragma unroll
    for (int e = 0; e < 16; e++) {
      s[e] = 1.f / (1.f + __expf(-acc[e]));       // sigmoid scores (weights)
      sc[e] = s[e] + ebias[e];                     // biased (selection only)
    }
    float gs[4];
#pragma unroll
    for (int g = 0; g < 4; g++) {                  // sum of top-2 per group of 4
      float a = -1e30f, b = -1e30f;
#pragma unroll
      for (int j = 0; j < 4; j++) {
        float v = sc[g*4 + j];
        if (v > a) { b = a; a = v; } else if (v > b) { b = v; }
      }
      gs[g] = a + b;
    }
    int g1 = 0;
    for (int g = 1; g < 4; g++) if (gs[g] > gs[g1]) g1 = g;   // ties -> lowest idx
    int g2 = -1;
    for (int g = 0; g < 4; g++) if (g != g1 && (g2 < 0 || gs[g] > gs[g2])) g2 = g;
    float masked[16];
#pragma unroll
    for (int e = 0; e < 16; e++) {
      int g = e >> 2;
      masked[e] = (g == g1 || g == g2) ? sc[e] : 0.0f;        // ref: unselected -> 0.0
    }
    int idx[4]; float wv[4]; float denom = 1e-20f;
#pragma unroll
    for (int j = 0; j < 4; j++) {
      int best = 0; float bv = masked[0];
      for (int e = 1; e < 16; e++) if (masked[e] > bv) { bv = masked[e]; best = e; }
      idx[j] = best; wv[j] = s[best]; denom += s[best];
      masked[best] = -1e30f;
    }
#pragma unroll
    for (int j = 0; j < 4; j++) {
      topk_i[t * 4 + j] = idx[j];
      topk_w[t * 4 + j] = wv[j] / denom * 2.5f;   // fold ROUTED_SCALE
    }
  }
}

// =============== scatter: per-expert lists + tiles + slot map (LDS atomics) ===============
__global__ __launch_bounds__(1024) void scatter_kernel(
    const int* __restrict__ tki,
    int* __restrict__ tok, int* __restrict__ slotmap,
    int* __restrict__ tile_e, int* __restrict__ tile_srow,
    int* __restrict__ tile_hb, int* __restrict__ ntl) {
  __shared__ int lcnt[NEXP], lpos[NEXP], lbase[NEXP];
  int t = threadIdx.x;                   // one thread per token
  if (t < NEXP) { lcnt[t] = 0; lpos[t] = 0; }
  __syncthreads();
  int idx[4];
#pragma unroll
  for (int j = 0; j < 4; j++) idx[j] = tki[t*4+j];
#pragma unroll
  for (int j = 0; j < 4; j++) atomicAdd(&lcnt[idx[j]], 1);
  __syncthreads();
  if (t == 0) {                          // tile metadata (tiny serial)
    int total = 0, slots = 0;
    for (int e = 0; e < NEXP; e++) {
      int c = lcnt[e], nt = (c + 63) >> 6;
      lbase[e] = slots;
      for (int j = 0; j < nt; j++) {
        tile_e[total] = e; tile_srow[total] = j * 64; tile_hb[total] = slots + j * 64; total++;
      }
      slots += nt * 64;
    }
    ntl[0] = total;
  }
  __syncthreads();
#pragma unroll
  for (int j = 0; j < 4; j++) {
    int slot = atomicAdd(&lpos[idx[j]], 1);
    tok[idx[j] * T_TOK + slot] = t;
    slotmap[t * 4 + j] = lbase[idx[j]] + slot;   // hbuf/odown row of this assignment
  }
  __syncthreads();
  // padding rows gather token 0 (results never read by combine)
  int e = t >> 6, s = t & 63;
  int c = lcnt[e];
  int top = ((c + 63) >> 6) << 6;
  if (c + s < top) tok[e * T_TOK + c + s] = 0;
}

// =============== GEMM cores: 64x64 tile, BK=64, 4 waves (2x2 of 32x32) ===============
__device__ __forceinline__ f32x4 mfma16(f16x8 a, f16x8 b, f32x4 c) {
  return __builtin_amdgcn_mfma_f32_16x16x32_f16(a, b, c, 0, 0, 0);
}

// gate+up with fused silu; shared (blocks 0..255) + routed gather (blocks 256..)
__global__ __launch_bounds__(256) void gu_all(
    const f16* __restrict__ xh,
    const f16* __restrict__ sgT, const f16* __restrict__ suT, f16* __restrict__ hsh,
    const f16* __restrict__ wgT, const f16* __restrict__ wuT, f16* __restrict__ hbuf,
    const int* __restrict__ tile_e, const int* __restrict__ tile_srow,
    const int* __restrict__ tile_hb, const int* __restrict__ ntl,
    const int* __restrict__ tok) {
  int b = blockIdx.x;
  const f16 *Bg, *Bu; f16* Hdst;
  int e = 0, srow = 0, mbase, n0, N;
  bool gather = (b >= 256);
  if (!gather) {
    Bg = sgT; Bu = suT; Hdst = hsh; N = ISH;
    n0 = (b & 15) * 64; mbase = (b >> 4) * 64;
  } else {
    int rb = b - 256, by = rb >> 3;
    if (by >= ntl[0]) return;
    e = tile_e[by]; srow = tile_srow[by]; mbase = tile_hb[by];
    size_t bo = (size_t)e * IDIM * HDIM;
    Bg = wgT + bo; Bu = wuT + bo; Hdst = hbuf; N = IDIM;
    n0 = (rb & 7) * 64;
  }
  const int K = HDIM;

  __shared__ f16 As[64 * 64], Bgs[64 * 64], Bus[64 * 64];

  int tid = threadIdx.x, lane = tid & 63, wave = tid >> 6;
  int quad = lane >> 4, l15 = lane & 15;
  int r = lane >> 3, p = lane & 7;

  const f16* gb[6]; f16* lb[6];
#pragma unroll
  for (int jj = 0; jj < 6; jj++) {
    int j = wave * 6 + jj;
    int buf = j >> 3, i = j & 7;
    int row = i * 8 + r;
    int kcol = (p ^ r) << 3;                       // swizzled k-chunk
    if (buf == 0) {
      int grow = gather ? tok[e * T_TOK + srow + row] : (mbase + row);
      gb[jj] = xh + (size_t)grow * K + kcol;       lb[jj] = (f16*)As + (i << 9);
    } else if (buf == 1) {
      gb[jj] = Bg + (size_t)(n0 + row) * K + kcol; lb[jj] = (f16*)Bgs + (i << 9);
    } else {
      gb[jj] = Bu + (size_t)(n0 + row) * K + kcol; lb[jj] = (f16*)Bus + (i << 9);
    }
  }

  int wr = wave >> 1, wc = wave & 1;
  int ar0 = 32 * wr + l15, br0 = 32 * wc + l15;
  f32x4 zero = {0.f, 0.f, 0.f, 0.f};
  f32x4 aG[2][2] = {{zero, zero}, {zero, zero}};
  f32x4 aU[2][2] = {{zero, zero}, {zero, zero}};

  for (int kt = 0; kt < K; kt += 64) {
    __syncthreads();
#pragma unroll
    for (int jj = 0; jj < 6; jj++) gld16(gb[jj] + kt, lb[jj]);
    __syncthreads();
#pragma unroll
    for (int ks = 0; ks < 2; ks++) {
      int lch = (ks << 2) + quad;
      f16x8 a0 = ldsfrag(As,  ar0,      lch);
      f16x8 a1 = ldsfrag(As,  ar0 + 16, lch);
      f16x8 g0 = ldsfrag(Bgs, br0,      lch);
      f16x8 g1 = ldsfrag(Bgs, br0 + 16, lch);
      f16x8 u0 = ldsfrag(Bus, br0,      lch);
      f16x8 u1 = ldsfrag(Bus, br0 + 16, lch);
      aG[0][0] = mfma16(a0, g0, aG[0][0]); aG[0][1] = mfma16(a0, g1, aG[0][1]);
      aG[1][0] = mfma16(a1, g0, aG[1][0]); aG[1][1] = mfma16(a1, g1, aG[1][1]);
      aU[0][0] = mfma16(a0, u0, aU[0][0]); aU[0][1] = mfma16(a0, u1, aU[0][1]);
      aU[1][0] = mfma16(a1, u0, aU[1][0]); aU[1][1] = mfma16(a1, u1, aU[1][1]);
    }
  }
#pragma unroll
  for (int mi = 0; mi < 2; mi++)
#pragma unroll
    for (int ni = 0; ni < 2; ni++)
#pragma unroll
      for (int rg = 0; rg < 4; rg++) {
        int m = 32 * wr + 16 * mi + (quad << 2) + rg;   // C/D: row = quad*4+reg
        int n = n0 + 32 * wc + 16 * ni + l15;           //      col = lane&15
        float g = aG[mi][ni][rg], u = aU[mi][ni][rg];
        float val = (g / (1.f + __expf(-g))) * u;
        Hdst[(size_t)(mbase + m) * N + n] = (f16)val;
      }
}

// down proj; shared (blocks 0..255) -> out fp32 stores; routed -> odown f16 stores
__global__ __launch_bounds__(256) void down_all(
    const f16* __restrict__ hsh, const f16* __restrict__ sdT,
    const f16* __restrict__ hbuf, const f16* __restrict__ wdT,
    float* __restrict__ out, f16* __restrict__ odown,
    const int* __restrict__ tile_e, const int* __restrict__ tile_srow,
    const int* __restrict__ tile_hb, const int* __restrict__ ntl) {
  int b = blockIdx.x;
  bool routed = (b >= 256);
  const f16 *A, *B; int K, abase, n0, e = 0;
  if (!routed) {
    A = hsh; B = sdT; K = ISH;
    abase = (b >> 4) * 64; n0 = (b & 15) * 64;
  } else {
    int rb = b - 256, by = rb >> 4;
    if (by >= ntl[0]) return;
    e = tile_e[by]; abase = tile_hb[by];
    A = hbuf; B = wdT + (size_t)e * HDIM * IDIM; K = IDIM;
    n0 = (rb & 15) * 64;
  }

  __shared__ f16 As[64 * 64], Bs[64 * 64];

  int tid = threadIdx.x, lane = tid & 63, wave = tid >> 6;
  int quad = lane >> 4, l15 = lane & 15;
  int r = lane >> 3, p = lane & 7;

  const f16* gb[4]; f16* lb[4];
#pragma unroll
  for (int jj = 0; jj < 4; jj++) {
    int j = wave * 4 + jj;
    int buf = j >> 3, i = j & 7;
    int row = i * 8 + r;
    int kcol = (p ^ r) << 3;
    if (buf == 0) { gb[jj] = A + (size_t)(abase + row) * K + kcol; lb[jj] = (f16*)As + (i << 9); }
    else          { gb[jj] = B + (size_t)(n0 + row) * K + kcol;    lb[jj] = (f16*)Bs + (i << 9); }
  }

  int wr = wave >> 1, wc = wave & 1;
  int ar0 = 32 * wr + l15, br0 = 32 * wc + l15;
  f32x4 zero = {0.f, 0.f, 0.f, 0.f};
  f32x4 ac[2][2] = {{zero, zero}, {zero, zero}};

  for (int kt = 0; kt < K; kt += 64) {
    __syncthreads();
#pragma unroll
    for (int jj = 0; jj < 4; jj++) gld16(gb[jj] + kt, lb[jj]);
    __syncthreads();
#pragma unroll
    for (int ks = 0; ks < 2; ks++) {
      int lch = (ks << 2) + quad;
      f16x8 a0 = ldsfrag(As, ar0,      lch);
      f16x8 a1 = ldsfrag(As, ar0 + 16, lch);
      f16x8 b0 = ldsfrag(Bs, br0,      lch);
      f16x8 b1 = ldsfrag(Bs, br0 + 16, lch);
      ac[0][0] = mfma16(a0, b0, ac[0][0]); ac[0][1] = mfma16(a0, b1, ac[0][1]);
      ac[1][0] = mfma16(a1, b0, ac[1][0]); ac[1][1] = mfma16(a1, b1, ac[1][1]);
    }
  }
#pragma unroll
  for (int mi = 0; mi < 2; mi++)
#pragma unroll
    for (int ni = 0; ni < 2; ni++)
#pragma unroll
      for (int rg = 0; rg < 4; rg++) {
        int m = 32 * wr + 16 * mi + (quad << 2) + rg;
        int n = n0 + 32 * wc + 16 * ni + l15;
        if (routed) odown[(size_t)(abase + m) * HDIM + n] = (f16)ac[mi][ni][rg];
        else        out  [(size_t)(abase + m) * HDIM + n] = ac[mi][ni][rg];
      }
}

// =============== combine: out[t] += sum_j w_j * odown[slot(t,j)] ===============
__global__ __launch_bounds__(256) void combine_kernel(
    const f16* __restrict__ odown, const int* __restrict__ slotmap,
    const float* __restrict__ tkw, float* __restrict__ out) {
  int t = blockIdx.x;
  __shared__ int ss[4]; __shared__ float sw[4];
  if (threadIdx.x < 4) {
    ss[threadIdx.x] = slotmap[t * 4 + threadIdx.x];
    sw[threadIdx.x] = tkw[t * 4 + threadIdx.x];
  }
  __syncthreads();
  int h = threadIdx.x * 4;
  float4 acc = *(const float4*)(out + (size_t)t * HDIM + h);
#pragma unroll
  for (int j = 0; j < 4; j++) {
    f16x4 v = *(const f16x4*)(odown + (size_t)ss[j] * HDIM + h);
    float wj = sw[j];
    acc.x += wj * (float)v[0]; acc.y += wj * (float)v[1];
    acc.z += wj * (float)v[2]; acc.w += wj * (float)v[3];
  }
  *(float4*)(out + (size_t)t * HDIM + h) = acc;
}

// =============== launch ===============
extern "C" void kernel_launch(void* const* d_in, const int* in_sizes, int n_in,
                              void* d_out, int out_size, void* d_ws, size_t ws_size,
                              hipStream_t stream) {
  const float* x  = (const float*)d_in[0];
  const float* rw = (const float*)d_in[1];
  const float* eb = (const float*)d_in[2];
  const float* wg = (const float*)d_in[3];
  const float* wu = (const float*)d_in[4];
  const float* wd = (const float*)d_in[5];
  const float* sg = (const float*)d_in[6];
  const float* su = (const float*)d_in[7];
  const float* sd = (const float*)d_in[8];
  float* out = (float*)d_out;
  (void)in_sizes; (void)n_in; (void)out_size; (void)ws_size;

  char* w = (char*)d_ws;
  size_t off = 0;
  auto alloc = [&](size_t b) { void* p = w + off; off = (off + b + 255) & ~(size_t)255; return p; };

  f16* xh   = (f16*)alloc((size_t)T_TOK * HDIM * 2);
  f16* wgT  = (f16*)alloc((size_t)NEXP * IDIM * HDIM * 2);
  f16* wuT  = (f16*)alloc((size_t)NEXP * IDIM * HDIM * 2);
  f16* wdT  = (f16*)alloc((size_t)NEXP * HDIM * IDIM * 2);
  f16* sgT  = (f16*)alloc((size_t)ISH * HDIM * 2);
  f16* suT  = (f16*)alloc((size_t)ISH * HDIM * 2);
  f16* sdT  = (f16*)alloc((size_t)HDIM * ISH * 2);
  f16* hbuf = (f16*)alloc((size_t)HSLOTS * IDIM * 2);
  f16* hsh  = (f16*)alloc((size_t)T_TOK * ISH * 2);
  int* topk_i = (int*)alloc((size_t)T_TOK * 4 * 4);
  float* topk_w = (float*)alloc((size_t)T_TOK * 4 * 4);
  int* tok  = (int*)alloc((size_t)NEXP * T_TOK * 4);
  int* slotmap = (int*)alloc((size_t)T_TOK * 4 * 4);
  int* tile_e    = (int*)alloc(MAXTILES * 4);
  int* tile_srow = (int*)alloc(MAXTILES * 4);
  int* tile_hb   = (int*)alloc(MAXTILES * 4);
  int* ntl       = (int*)alloc(16);
  // odown (f16, HSLOTS x HDIM = 10 MB) aliases wgT (16 MB): wgT is dead after
  // gu_all completes, and down_all (writer) is stream-ordered after it.
  f16* odown = (f16*)wgT;

  transpose_all<<<dim3(16, 16, 51), 256, 0, stream>>>(wg, wu, wd, sg, su, sd,
                                                      wgT, wuT, wdT, sgT, suT, sdT);
  router_kernel<<<T_TOK / 4, 256, 0, stream>>>(x, rw, eb, xh, topk_i, topk_w);
  scatter_kernel<<<1, 1024, 0, stream>>>(topk_i, tok, slotmap,
                                         tile_e, tile_srow, tile_hb, ntl);
  // shared gu (256 blocks) + routed gu (640 blocks) in one dispatch
  gu_all<<<256 + (MAXTILES - 16) * 8, 256, 0, stream>>>(
      xh, sgT, suT, hsh, wgT, wuT, hbuf, tile_e, tile_srow, tile_hb, ntl, tok);
  // shared down (256) -> out fp32; routed down (1280) -> odown f16
  down_all<<<256 + (MAXTILES - 16) * 16, 256, 0, stream>>>(
      hsh, sdT, hbuf, wdT, out, odown, tile_e, tile_srow, tile_hb, ntl);
  // out[t] += sum_j w_j * odown[slot]
  combine_kernel<<<T_TOK, 256, 0, stream>>>(odown, slotmap, topk_w, out);
}